// Round 4
// baseline (2646.577 us; speedup 1.0000x reference)
//
#include <hip/hip_runtime.h>

#define NPTS   16384
#define KCODES 8192
#define DDIM   256
#define HWSZ   1024
#define CHW    (DDIM * HWSZ)          // 262144
#define OUT_ELEMS 4194304
#define LOSS_OFF  OUT_ELEMS
#define IDX_OFF   (OUT_ELEMS + 1)

#define PT 32            // points per block
#define KT 1024          // codes per pass
#define DK 8             // d-chunk staged in LDS
#define NPASS  (KCODES / KT)    // 8
#define NCHUNK (DDIM / DK)      // 32
#define NITER  (NPASS * NCHUNK) // 256
#define PW     (DK * KT)        // 8192 words per pool buffer

// swizzled transposed e-tile: element (d, k) -> buf[d*KT + ((((k>>2) ^ d) << 2) | (k&3))]
// staging writes: 2-way per bank (free). b128 reads: <=2-way per 16-lane phase (free).

__launch_bounds__(512, 4)
__global__ void vq_kernel(const float* __restrict__ x,
                          const float* __restrict__ emb,
                          float* __restrict__ out)
{
    __shared__ float  pool[2][PW];   // 65536 B: double-buffered e chunk
    __shared__ float  ldsSE[KT];     // 4096 B: ||e||^2 per code of current pass
    __shared__ float  ldsS[PT];
    __shared__ int    ldsI[PT];
    __shared__ float  ldsFD[64];     // 8 waves x 8 points: final argmin stage
    __shared__ int    ldsFI[64];
    __shared__ double ldsL[8];

    const int t   = threadIdx.x;
    const int n0  = blockIdx.x * PT;
    const int b   = n0 / HWSZ;
    const int hw0 = n0 % HWSZ;
    const float* xs = x + (size_t)b * CHW + hw0;   // xs[c*HWSZ + p] = x[b][c][hw0+p]

    const int kq = t >> 1;          // staging code base (0..255), +256*i
    const int dh = (t & 1) * 4;     // staging d-half {0,4}

    // ---- prefetch e chunk 0 ----
    float4 stg[4];
    {
        const float* src = emb + (size_t)kq * DDIM + dh;
        #pragma unroll
        for (int i = 0; i < 4; ++i)
            stg[i] = *(const float4*)(src + (size_t)i * 256 * DDIM);
    }

    // ---- prologue: s[p] = ||x_p||^2 (fp32 FMA; per-point-constant error cancels in argmin) ----
    {
        const int p   = t & 31;
        const int seg = t >> 5;                    // 0..15, 16 channels each
        float a = 0.0f;
        for (int i = 0; i < 16; ++i) {
            const float v = xs[(size_t)(seg * 16 + i) * HWSZ + p];
            a = fmaf(v, v, a);
        }
        pool[0][seg * 33 + p] = a;                 // scratch in buf0 (pre-loop)
    }
    __syncthreads();
    if (t < PT) {
        float s = 0.0f;
        for (int g = 0; g < 16; ++g) s += pool[0][g * 33 + t];
        ldsS[t] = s;
    }
    __syncthreads();

    const int kg  = t & 127;                       // codes 4kg..4kg+3 (L), +512 (H)
    const int p0  = (t >> 7) * 8;                  // 8 points, wave-uniform
    const int p0u = __builtin_amdgcn_readfirstlane(p0);
    const float* xu = xs + p0u;

    float best_d[8];
    int   best_i[8];
    #pragma unroll
    for (int i = 0; i < 8; ++i) { best_d[i] = 3.4e38f; best_i[i] = 0; }

    float4 accL[8], accH[8];
    float  se_reg[4] = {0.f, 0.f, 0.f, 0.f};

    for (int c = 0; c < NITER; ++c) {
        float* buf = pool[c & 1];
        if ((c & 31) == 0) {
            #pragma unroll
            for (int i = 0; i < 8; ++i) {
                accL[i] = make_float4(0.f, 0.f, 0.f, 0.f);
                accH[i] = make_float4(0.f, 0.f, 0.f, 0.f);
            }
        }
        // ---- stage chunk c from regs into swizzled transpose; SE reg accumulate ----
        #pragma unroll
        for (int i = 0; i < 4; ++i) {
            const int k = kq + 256 * i;            // local code 0..1023
            const int g = k >> 2;
            const int m = k & 3;
            const float4 v = stg[i];
            buf[(dh + 0) * KT + (((g ^ (dh + 0)) << 2) | m)] = v.x;
            buf[(dh + 1) * KT + (((g ^ (dh + 1)) << 2) | m)] = v.y;
            buf[(dh + 2) * KT + (((g ^ (dh + 2)) << 2) | m)] = v.z;
            buf[(dh + 3) * KT + (((g ^ (dh + 3)) << 2) | m)] = v.w;
            float ps = v.x * v.x;
            ps = fmaf(v.y, v.y, ps);
            ps = fmaf(v.z, v.z, ps);
            ps = fmaf(v.w, v.w, ps);
            se_reg[i] += ps;
        }
        if ((c & 31) == 31) {                      // pass's last chunk: publish SE
            #pragma unroll
            for (int i = 0; i < 4; ++i) {
                const float tot = se_reg[i] + __shfl_xor(se_reg[i], 1);
                if ((t & 1) == 0) ldsSE[kq + 256 * i] = tot;
                se_reg[i] = 0.f;
            }
        }
        __syncthreads();   // staged tile visible; nothing outstanding to drain
        // ---- prefetch chunk c+1 (post-barrier: barrier never waits on it) ----
        {
            int nc = c + 1;
            if (nc == NITER) nc = 0;               // harmless dummy
            const int npass = nc >> 5, nch = nc & 31;
            const float* src = emb + ((size_t)(npass * KT + kq) * DDIM) + nch * DK + dh;
            #pragma unroll
            for (int i = 0; i < 4; ++i)
                stg[i] = *(const float4*)(src + (size_t)i * 256 * DDIM);
        }
        // ---- compute chunk c: 8 pts x 8 codes x 8 d ----
        {
            const float* xdp = xu + (size_t)((c & 31) * DK) * HWSZ;
            #pragma unroll
            for (int dd = 0; dd < 8; ++dd) {
                const int go = (kg ^ dd) << 2;
                const float4 eL = *(const float4*)&buf[dd * KT + go];
                const float4 eH = *(const float4*)&buf[dd * KT + go + 512];
                const float4 xa = *(const float4*)(xdp + (size_t)dd * HWSZ);      // p0..p0+3
                const float4 xb = *(const float4*)(xdp + (size_t)dd * HWSZ + 4);  // p0+4..p0+7
                #pragma unroll
                for (int p = 0; p < 4; ++p) {
                    const float xsc = ((const float*)&xa)[p];
                    accL[p].x = fmaf(xsc, eL.x, accL[p].x);
                    accL[p].y = fmaf(xsc, eL.y, accL[p].y);
                    accL[p].z = fmaf(xsc, eL.z, accL[p].z);
                    accL[p].w = fmaf(xsc, eL.w, accL[p].w);
                    accH[p].x = fmaf(xsc, eH.x, accH[p].x);
                    accH[p].y = fmaf(xsc, eH.y, accH[p].y);
                    accH[p].z = fmaf(xsc, eH.z, accH[p].z);
                    accH[p].w = fmaf(xsc, eH.w, accH[p].w);
                }
                #pragma unroll
                for (int p = 4; p < 8; ++p) {
                    const float xsc = ((const float*)&xb)[p - 4];
                    accL[p].x = fmaf(xsc, eL.x, accL[p].x);
                    accL[p].y = fmaf(xsc, eL.y, accL[p].y);
                    accL[p].z = fmaf(xsc, eL.z, accL[p].z);
                    accL[p].w = fmaf(xsc, eL.w, accL[p].w);
                    accH[p].x = fmaf(xsc, eH.x, accH[p].x);
                    accH[p].y = fmaf(xsc, eH.y, accH[p].y);
                    accH[p].z = fmaf(xsc, eH.z, accH[p].z);
                    accH[p].w = fmaf(xsc, eH.w, accH[p].w);
                }
            }
        }
        // ---- pass finalize: dist = fl(fl(s+se) - 2m), ascending code index ----
        if ((c & 31) == 31) {
            const int kbase = (c >> 5) * KT;
            #pragma unroll
            for (int j = 0; j < 4; ++j) {          // L half first (smaller indices)
                const float se = ldsSE[4 * kg + j];
                const int   ki = kbase + 4 * kg + j;
                #pragma unroll
                for (int i = 0; i < 8; ++i) {
                    const float T = ldsS[p0 + i] + se;
                    const float d = fmaf(-2.0f, ((const float*)&accL[i])[j], T);
                    if (d < best_d[i]) { best_d[i] = d; best_i[i] = ki; }
                }
            }
            #pragma unroll
            for (int j = 0; j < 4; ++j) {          // H half
                const float se = ldsSE[512 + 4 * kg + j];
                const int   ki = kbase + 512 + 4 * kg + j;
                #pragma unroll
                for (int i = 0; i < 8; ++i) {
                    const float T = ldsS[p0 + i] + se;
                    const float d = fmaf(-2.0f, ((const float*)&accH[i])[j], T);
                    if (d < best_d[i]) { best_d[i] = d; best_i[i] = ki; }
                }
            }
        }
    }

    // ---- wave butterfly argmin (lexicographic), then cross-wave via LDS ----
    #pragma unroll
    for (int off = 1; off < 64; off <<= 1) {
        #pragma unroll
        for (int i = 0; i < 8; ++i) {
            const float d2 = __shfl_xor(best_d[i], off);
            const int   i2 = __shfl_xor(best_i[i], off);
            if (d2 < best_d[i] || (d2 == best_d[i] && i2 < best_i[i])) {
                best_d[i] = d2; best_i[i] = i2;
            }
        }
    }
    if ((t & 63) == 0) {
        const int w = t >> 6;
        #pragma unroll
        for (int i = 0; i < 8; ++i) { ldsFD[w * 8 + i] = best_d[i]; ldsFI[w * 8 + i] = best_i[i]; }
    }
    __syncthreads();
    if (t < PT) {
        const int pg = t >> 3, i = t & 7;
        float bd = ldsFD[(2 * pg) * 8 + i];
        int   bi = ldsFI[(2 * pg) * 8 + i];
        const float d2 = ldsFD[(2 * pg + 1) * 8 + i];
        const int   i2 = ldsFI[(2 * pg + 1) * 8 + i];
        if (d2 < bd || (d2 == bd && i2 < bi)) { bd = d2; bi = i2; }
        ldsI[t] = bi;
        out[(size_t)IDX_OFF + n0 + t] = (float)bi;
    }
    __syncthreads();

    // ---- epilogue: gather e row, straight-through out, loss partial ----
    double lsum = 0.0;
    {
        const int p  = t & 31;
        const int cg = t >> 5;                     // 0..15
        const int row = ldsI[p];
        const float* erow = emb + (size_t)row * DDIM;
        float* ob = out + (size_t)b * CHW + hw0 + p;
        for (int q = 0; q < 16; ++q) {
            const int c = cg * 16 + q;
            const float e  = erow[c];
            const float xx = xs[(size_t)c * HWSZ + p];
            const float diff = e - xx;             // fl(x_q - xt)
            ob[(size_t)c * HWSZ] = xx + diff;      // straight-through rounding
            lsum += (double)diff * (double)diff;
        }
    }
    #pragma unroll
    for (int off = 32; off > 0; off >>= 1)
        lsum += __shfl_xor(lsum, off);
    if ((t & 63) == 0) ldsL[t >> 6] = lsum;
    __syncthreads();
    if (t == 0) {
        double tot = 0.0;
        #pragma unroll
        for (int wv = 0; wv < 8; ++wv) tot += ldsL[wv];
        atomicAdd(&out[LOSS_OFF], (float)(tot * (1.25 / 4194304.0)));
    }
}

extern "C" void kernel_launch(void* const* d_in, const int* in_sizes, int n_in,
                              void* d_out, int out_size, void* d_ws, size_t ws_size,
                              hipStream_t stream) {
    (void)in_sizes; (void)n_in; (void)ws_size; (void)d_ws; (void)out_size;
    const float* x   = (const float*)d_in[0];
    const float* emb = (const float*)d_in[1];
    float* out = (float*)d_out;
    hipMemsetAsync((char*)d_out + (size_t)LOSS_OFF * sizeof(float), 0, sizeof(float), stream);
    vq_kernel<<<NPTS / PT, 512, 0, stream>>>(x, emb, out);
}

// Round 5
// 999.915 us; speedup vs baseline: 2.6468x; 2.6468x over previous
//
#include <hip/hip_runtime.h>

#define NPTS   16384
#define KCODES 8192
#define DDIM   256
#define HWSZ   1024
#define CHW    (DDIM * HWSZ)          // 262144
#define OUT_ELEMS 4194304
#define LOSS_OFF  OUT_ELEMS
#define IDX_OFF   (OUT_ELEMS + 1)

#define PT 32            // points per block
#define KT 1024          // codes per pass
#define DK 8             // d-chunk staged in LDS
#define NPASS  (KCODES / KT)    // 8
#define NCHUNK (DDIM / DK)      // 32
#define NITER  (NPASS * NCHUNK) // 256
#define PW     (DK * KT)        // 8192 words per pool buffer

// swizzled transposed e-tile: element (d, k) -> buf[d*KT + ((((k>>2) ^ d) << 2) | (k&3))]
// staging writes: 2-way per bank (free). b128 reads: <=2-way per 16-lane phase (free).
// NOTE: no second __launch_bounds__ arg — on this toolchain it acts like CUDA
// min-blocks/CU and capped VGPRs at 64 (R4: 3.8 GB of spill traffic).

__launch_bounds__(512)
__global__ void vq_kernel(const float* __restrict__ x,
                          const float* __restrict__ emb,
                          float* __restrict__ out)
{
    __shared__ float  pool[2][PW];   // 65536 B: double-buffered e chunk
    __shared__ float  ldsSE[KT];     // 4096 B: ||e||^2 per code of current pass
    __shared__ float  ldsS[PT];
    __shared__ int    ldsI[PT];
    __shared__ float  ldsFD[64];     // 8 waves x 8 points: final argmin stage
    __shared__ int    ldsFI[64];
    __shared__ double ldsL[8];

    const int t   = threadIdx.x;
    const int n0  = blockIdx.x * PT;
    const int b   = n0 / HWSZ;
    const int hw0 = n0 % HWSZ;
    const float* xs = x + (size_t)b * CHW + hw0;   // xs[c*HWSZ + p] = x[b][c][hw0+p]

    const int kq = t >> 1;          // staging code base (0..255), +256*i
    const int dh = (t & 1) * 4;     // staging d-half {0,4}

    // ---- prefetch e chunk 0 ----
    float4 stg[4];
    {
        const float* src = emb + (size_t)kq * DDIM + dh;
        #pragma unroll
        for (int i = 0; i < 4; ++i)
            stg[i] = *(const float4*)(src + (size_t)i * 256 * DDIM);
    }

    // ---- prologue: s[p] = ||x_p||^2 (fp32 FMA; per-point-constant error cancels in argmin) ----
    {
        const int p   = t & 31;
        const int seg = t >> 5;                    // 0..15, 16 channels each
        float a = 0.0f;
        for (int i = 0; i < 16; ++i) {
            const float v = xs[(size_t)(seg * 16 + i) * HWSZ + p];
            a = fmaf(v, v, a);
        }
        pool[0][seg * 33 + p] = a;                 // scratch in buf0 (pre-loop)
    }
    __syncthreads();
    if (t < PT) {
        float s = 0.0f;
        for (int g = 0; g < 16; ++g) s += pool[0][g * 33 + t];
        ldsS[t] = s;
    }
    __syncthreads();

    const int kg  = t & 127;                       // codes 4kg..4kg+3 (L), +512 (H)
    const int p0  = (t >> 7) * 8;                  // 8 points, wave-uniform
    const int p0u = __builtin_amdgcn_readfirstlane(p0);
    const float* xu = xs + p0u;

    float best_d[8];
    int   best_i[8];
    #pragma unroll
    for (int i = 0; i < 8; ++i) { best_d[i] = 3.4e38f; best_i[i] = 0; }

    float4 accL[8], accH[8];
    float  se_reg[4] = {0.f, 0.f, 0.f, 0.f};

    for (int c = 0; c < NITER; ++c) {
        float* buf = pool[c & 1];
        if ((c & 31) == 0) {
            #pragma unroll
            for (int i = 0; i < 8; ++i) {
                accL[i] = make_float4(0.f, 0.f, 0.f, 0.f);
                accH[i] = make_float4(0.f, 0.f, 0.f, 0.f);
            }
        }
        // ---- stage chunk c from regs into swizzled transpose; SE reg accumulate ----
        #pragma unroll
        for (int i = 0; i < 4; ++i) {
            const int k = kq + 256 * i;            // local code 0..1023
            const int g = k >> 2;
            const int m = k & 3;
            const float4 v = stg[i];
            buf[(dh + 0) * KT + (((g ^ (dh + 0)) << 2) | m)] = v.x;
            buf[(dh + 1) * KT + (((g ^ (dh + 1)) << 2) | m)] = v.y;
            buf[(dh + 2) * KT + (((g ^ (dh + 2)) << 2) | m)] = v.z;
            buf[(dh + 3) * KT + (((g ^ (dh + 3)) << 2) | m)] = v.w;
            float ps = v.x * v.x;
            ps = fmaf(v.y, v.y, ps);
            ps = fmaf(v.z, v.z, ps);
            ps = fmaf(v.w, v.w, ps);
            se_reg[i] += ps;
        }
        if ((c & 31) == 31) {                      // pass's last chunk: publish SE
            #pragma unroll
            for (int i = 0; i < 4; ++i) {
                const float tot = se_reg[i] + __shfl_xor(se_reg[i], 1);
                if ((t & 1) == 0) ldsSE[kq + 256 * i] = tot;
                se_reg[i] = 0.f;
            }
        }
        __syncthreads();   // staged tile visible; nothing outstanding to drain
        // ---- prefetch chunk c+1 (post-barrier: barrier never waits on it) ----
        {
            int nc = c + 1;
            if (nc == NITER) nc = 0;               // harmless dummy
            const int npass = nc >> 5, nch = nc & 31;
            const float* src = emb + ((size_t)(npass * KT + kq) * DDIM) + nch * DK + dh;
            #pragma unroll
            for (int i = 0; i < 4; ++i)
                stg[i] = *(const float4*)(src + (size_t)i * 256 * DDIM);
        }
        // ---- compute chunk c: 8 pts x 8 codes x 8 d ----
        {
            const float* xdp = xu + (size_t)((c & 31) * DK) * HWSZ;
            #pragma unroll
            for (int dd = 0; dd < 8; ++dd) {
                const int go = (kg ^ dd) << 2;
                const float4 eL = *(const float4*)&buf[dd * KT + go];
                const float4 eH = *(const float4*)&buf[dd * KT + go + 512];
                const float4 xa = *(const float4*)(xdp + (size_t)dd * HWSZ);      // p0..p0+3
                const float4 xb = *(const float4*)(xdp + (size_t)dd * HWSZ + 4);  // p0+4..p0+7
                #pragma unroll
                for (int p = 0; p < 4; ++p) {
                    const float xsc = ((const float*)&xa)[p];
                    accL[p].x = fmaf(xsc, eL.x, accL[p].x);
                    accL[p].y = fmaf(xsc, eL.y, accL[p].y);
                    accL[p].z = fmaf(xsc, eL.z, accL[p].z);
                    accL[p].w = fmaf(xsc, eL.w, accL[p].w);
                    accH[p].x = fmaf(xsc, eH.x, accH[p].x);
                    accH[p].y = fmaf(xsc, eH.y, accH[p].y);
                    accH[p].z = fmaf(xsc, eH.z, accH[p].z);
                    accH[p].w = fmaf(xsc, eH.w, accH[p].w);
                }
                #pragma unroll
                for (int p = 4; p < 8; ++p) {
                    const float xsc = ((const float*)&xb)[p - 4];
                    accL[p].x = fmaf(xsc, eL.x, accL[p].x);
                    accL[p].y = fmaf(xsc, eL.y, accL[p].y);
                    accL[p].z = fmaf(xsc, eL.z, accL[p].z);
                    accL[p].w = fmaf(xsc, eL.w, accL[p].w);
                    accH[p].x = fmaf(xsc, eH.x, accH[p].x);
                    accH[p].y = fmaf(xsc, eH.y, accH[p].y);
                    accH[p].z = fmaf(xsc, eH.z, accH[p].z);
                    accH[p].w = fmaf(xsc, eH.w, accH[p].w);
                }
            }
        }
        // ---- pass finalize: dist = fl(fl(s+se) - 2m), ascending code index ----
        if ((c & 31) == 31) {
            const int kbase = (c >> 5) * KT;
            #pragma unroll
            for (int j = 0; j < 4; ++j) {          // L half first (smaller indices)
                const float se = ldsSE[4 * kg + j];
                const int   ki = kbase + 4 * kg + j;
                #pragma unroll
                for (int i = 0; i < 8; ++i) {
                    const float T = ldsS[p0 + i] + se;
                    const float d = fmaf(-2.0f, ((const float*)&accL[i])[j], T);
                    if (d < best_d[i]) { best_d[i] = d; best_i[i] = ki; }
                }
            }
            #pragma unroll
            for (int j = 0; j < 4; ++j) {          // H half
                const float se = ldsSE[512 + 4 * kg + j];
                const int   ki = kbase + 512 + 4 * kg + j;
                #pragma unroll
                for (int i = 0; i < 8; ++i) {
                    const float T = ldsS[p0 + i] + se;
                    const float d = fmaf(-2.0f, ((const float*)&accH[i])[j], T);
                    if (d < best_d[i]) { best_d[i] = d; best_i[i] = ki; }
                }
            }
        }
    }

    // ---- wave butterfly argmin (lexicographic), then cross-wave via LDS ----
    #pragma unroll
    for (int off = 1; off < 64; off <<= 1) {
        #pragma unroll
        for (int i = 0; i < 8; ++i) {
            const float d2 = __shfl_xor(best_d[i], off);
            const int   i2 = __shfl_xor(best_i[i], off);
            if (d2 < best_d[i] || (d2 == best_d[i] && i2 < best_i[i])) {
                best_d[i] = d2; best_i[i] = i2;
            }
        }
    }
    if ((t & 63) == 0) {
        const int w = t >> 6;
        #pragma unroll
        for (int i = 0; i < 8; ++i) { ldsFD[w * 8 + i] = best_d[i]; ldsFI[w * 8 + i] = best_i[i]; }
    }
    __syncthreads();
    if (t < PT) {
        const int pg = t >> 3, i = t & 7;
        float bd = ldsFD[(2 * pg) * 8 + i];
        int   bi = ldsFI[(2 * pg) * 8 + i];
        const float d2 = ldsFD[(2 * pg + 1) * 8 + i];
        const int   i2 = ldsFI[(2 * pg + 1) * 8 + i];
        if (d2 < bd || (d2 == bd && i2 < bi)) { bd = d2; bi = i2; }
        ldsI[t] = bi;
        out[(size_t)IDX_OFF + n0 + t] = (float)bi;
    }
    __syncthreads();

    // ---- epilogue: gather e row, straight-through out, loss partial ----
    double lsum = 0.0;
    {
        const int p  = t & 31;
        const int cg = t >> 5;                     // 0..15
        const int row = ldsI[p];
        const float* erow = emb + (size_t)row * DDIM;
        float* ob = out + (size_t)b * CHW + hw0 + p;
        for (int q = 0; q < 16; ++q) {
            const int c = cg * 16 + q;
            const float e  = erow[c];
            const float xx = xs[(size_t)c * HWSZ + p];
            const float diff = e - xx;             // fl(x_q - xt)
            ob[(size_t)c * HWSZ] = xx + diff;      // straight-through rounding
            lsum += (double)diff * (double)diff;
        }
    }
    #pragma unroll
    for (int off = 32; off > 0; off >>= 1)
        lsum += __shfl_xor(lsum, off);
    if ((t & 63) == 0) ldsL[t >> 6] = lsum;
    __syncthreads();
    if (t == 0) {
        double tot = 0.0;
        #pragma unroll
        for (int wv = 0; wv < 8; ++wv) tot += ldsL[wv];
        atomicAdd(&out[LOSS_OFF], (float)(tot * (1.25 / 4194304.0)));
    }
}

extern "C" void kernel_launch(void* const* d_in, const int* in_sizes, int n_in,
                              void* d_out, int out_size, void* d_ws, size_t ws_size,
                              hipStream_t stream) {
    (void)in_sizes; (void)n_in; (void)ws_size; (void)d_ws; (void)out_size;
    const float* x   = (const float*)d_in[0];
    const float* emb = (const float*)d_in[1];
    float* out = (float*)d_out;
    hipMemsetAsync((char*)d_out + (size_t)LOSS_OFF * sizeof(float), 0, sizeof(float), stream);
    vq_kernel<<<NPTS / PT, 512, 0, stream>>>(x, emb, out);
}